// Round 1
// baseline (869.570 us; speedup 1.0000x reference)
//
#include <hip/hip_runtime.h>
#include <hip/hip_bf16.h>

// Problem constants (from reference)
#define N_STAGES   400
#define N_CLASSES  10
#define N_TREES    4000          // N_STAGES * N_CLASSES
#define DEPTH      6
#define N_INTERNAL 63
#define N_LEAVES   64
#define N_FEATURES 128
#define BATCH      32768
#define LR         0.1f

// Kernel config
#define BLOCK      256
#define J_SPLIT    8                       // threads per sample
#define SAMPLES_PB (BLOCK / J_SPLIT)       // 32 samples per block
#define TREES_PT   (N_TREES / J_SPLIT)     // 500 trees per thread
#define UNROLL     10                      // trees in flight per thread (class = u)

// Pack (feature, threshold) into int2, padded to 64 nodes per tree (512 B stride)
__global__ void pack_nodes_kernel(const int* __restrict__ features,
                                  const float* __restrict__ thresholds,
                                  int2* __restrict__ nodes) {
    int i = blockIdx.x * blockDim.x + threadIdx.x;
    if (i < N_TREES * N_INTERNAL) {
        int t = i / N_INTERNAL;
        int n = i - t * N_INTERNAL;
        nodes[(t << 6) + n] = make_int2(features[i], __float_as_int(thresholds[i]));
    }
}

template <bool PACKED>
__global__ __launch_bounds__(BLOCK, 4) void gbt_eval_kernel(
    const float* __restrict__ x,
    const int2*  __restrict__ nodes,        // PACKED path, stride 64
    const int*   __restrict__ features,     // fallback path, stride 63
    const float* __restrict__ thresholds,   // fallback path, stride 63
    const float* __restrict__ leaf_values,  // [N_TREES][64]
    const float* __restrict__ init_out,     // [10]
    float*       __restrict__ out)          // [BATCH][10]
{
    __shared__ float xs[SAMPLES_PB * N_FEATURES];      // 16 KB
    __shared__ float sums[SAMPLES_PB * N_CLASSES];     // 1.25 KB

    const int tid = threadIdx.x;
    const int sample0 = blockIdx.x * SAMPLES_PB;

    // Stage x rows for this block's 32 samples (contiguous 16 KB, float4 coalesced)
    {
        const float4* xg = (const float4*)(x + (size_t)sample0 * N_FEATURES);
        float4* xs4 = (float4*)xs;
        #pragma unroll
        for (int i = tid; i < SAMPLES_PB * (N_FEATURES / 4); i += BLOCK)
            xs4[i] = xg[i];
    }
    for (int i = tid; i < SAMPLES_PB * N_CLASSES; i += BLOCK)
        sums[i] = 0.0f;
    __syncthreads();

    // Lane layout: sLocal = tid & 31 (so 32 lanes of a wave walk the SAME tree
    // -> node loads span <=504 B, 2-4 cache lines), j = tid >> 5 picks tree chunk.
    const int sLocal = tid & (SAMPLES_PB - 1);
    const int j      = tid >> 5;                 // 0..7
    const float* xrow = xs + sLocal * N_FEATURES;
    const int t0 = j * TREES_PT;                 // multiple of 10 -> class = u

    float acc[N_CLASSES];
    #pragma unroll
    for (int k = 0; k < N_CLASSES; ++k) acc[k] = 0.0f;

    for (int i = 0; i < TREES_PT; i += UNROLL) {
        const int tt = t0 + i;
        int idx[UNROLL];
        #pragma unroll
        for (int u = 0; u < UNROLL; ++u) idx[u] = 0;

        #pragma unroll
        for (int d = 0; d < DEPTH; ++d) {
            int   f[UNROLL];
            float thr[UNROLL];
            #pragma unroll
            for (int u = 0; u < UNROLL; ++u) {
                if (PACKED) {
                    int2 nd = nodes[((tt + u) << 6) + idx[u]];
                    f[u]   = nd.x;
                    thr[u] = __int_as_float(nd.y);
                } else {
                    int base = (tt + u) * N_INTERNAL + idx[u];
                    f[u]   = features[base];
                    thr[u] = thresholds[base];
                }
            }
            float xv[UNROLL];
            #pragma unroll
            for (int u = 0; u < UNROLL; ++u) xv[u] = xrow[f[u]];
            #pragma unroll
            for (int u = 0; u < UNROLL; ++u)
                idx[u] = 2 * idx[u] + 1 + (xv[u] > thr[u] ? 1 : 0);
        }
        #pragma unroll
        for (int u = 0; u < UNROLL; ++u) {
            float lv = leaf_values[((size_t)(tt + u) << 6) + (idx[u] - N_INTERNAL)];
            acc[u] += lv;   // tree (tt+u) % 10 == u  -> class u
        }
    }

    #pragma unroll
    for (int k = 0; k < N_CLASSES; ++k)
        atomicAdd(&sums[sLocal * N_CLASSES + k], acc[k]);
    __syncthreads();

    for (int e = tid; e < SAMPLES_PB * N_CLASSES; e += BLOCK) {
        int s = e / N_CLASSES;
        int k = e - s * N_CLASSES;
        out[(size_t)(sample0 + s) * N_CLASSES + k] = init_out[k] + LR * sums[e];
    }
}

extern "C" void kernel_launch(void* const* d_in, const int* in_sizes, int n_in,
                              void* d_out, int out_size, void* d_ws, size_t ws_size,
                              hipStream_t stream) {
    const float* x          = (const float*)d_in[0];
    const int*   features   = (const int*)d_in[1];
    const float* thresholds = (const float*)d_in[2];
    const float* leafvals   = (const float*)d_in[3];
    const float* init_out   = (const float*)d_in[4];
    float*       out        = (float*)d_out;

    const size_t packed_bytes = (size_t)N_TREES * 64 * sizeof(int2);  // 2 MB
    const int grid = BATCH / SAMPLES_PB;                              // 1024

    if (ws_size >= packed_bytes) {
        int2* nodes = (int2*)d_ws;
        int n = N_TREES * N_INTERNAL;
        pack_nodes_kernel<<<(n + 255) / 256, 256, 0, stream>>>(features, thresholds, nodes);
        gbt_eval_kernel<true><<<grid, BLOCK, 0, stream>>>(
            x, nodes, nullptr, nullptr, leafvals, init_out, out);
    } else {
        gbt_eval_kernel<false><<<grid, BLOCK, 0, stream>>>(
            x, nullptr, features, thresholds, leafvals, init_out, out);
    }
}

// Round 2
// 510.249 us; speedup vs baseline: 1.7042x; 1.7042x over previous
//
#include <hip/hip_runtime.h>
#include <hip/hip_bf16.h>

// Problem constants (from reference)
#define N_STAGES   400
#define N_CLASSES  10
#define N_TREES    4000          // N_STAGES * N_CLASSES
#define DEPTH      6
#define N_INTERNAL 63
#define N_LEAVES   64
#define N_FEATURES 128
#define BATCH      32768
#define LR         0.1f

// Kernel config
#define BLOCK      256
#define J_SPLIT    8                       // threads per sample
#define SAMPLES_PB (BLOCK / J_SPLIT)       // 32 samples per block
#define TREES_PT   (N_TREES / J_SPLIT)     // 500 trees per thread
#define UNROLL     10                      // trees in flight per thread (class = u)

// Pack (feature, threshold) into int2, padded to 64 nodes per tree (512 B stride)
__global__ void pack_nodes_kernel(const int* __restrict__ features,
                                  const float* __restrict__ thresholds,
                                  int2* __restrict__ nodes) {
    int i = blockIdx.x * blockDim.x + threadIdx.x;
    if (i < N_TREES * N_INTERNAL) {
        int t = i / N_INTERNAL;
        int n = i - t * N_INTERNAL;
        nodes[(t << 6) + n] = make_int2(features[i], __float_as_int(thresholds[i]));
    }
}

template <bool PACKED>
__global__ __launch_bounds__(BLOCK, 4) void gbt_eval_kernel(
    const float* __restrict__ x,
    const int2*  __restrict__ nodes,        // PACKED path, stride 64
    const int*   __restrict__ features,     // fallback path, stride 63
    const float* __restrict__ thresholds,   // fallback path, stride 63
    const float* __restrict__ leaf_values,  // [N_TREES][64]
    const float* __restrict__ init_out,     // [10]
    float*       __restrict__ out)          // [BATCH][10]
{
    // TRANSPOSED x tile: xs[f * 32 + sLocal]. Bank = sLocal % 32, so a wave
    // whose lanes share f (same tree node, different samples) hits 32 distinct
    // banks (2-way alias across the two half-waves = free). This removes the
    // 64-way conflicts of the [sample][feature] layout (R1: 4.36e8 conflict cyc).
    __shared__ float xs[N_FEATURES * SAMPLES_PB];      // 16 KB
    __shared__ float sums[SAMPLES_PB * N_CLASSES];     // 1.25 KB

    const int tid = threadIdx.x;
    const int sample0 = blockIdx.x * SAMPLES_PB;

    // Stage x rows (coalesced float4 global reads; LDS writes are ~32-way
    // conflicted but only 4 iterations once per block -- negligible).
    {
        const float4* xg = (const float4*)(x + (size_t)sample0 * N_FEATURES);
        for (int e = tid; e < SAMPLES_PB * (N_FEATURES / 4); e += BLOCK) {
            int s  = e >> 5;          // sample row (32 float4 per row)
            int f4 = e & 31;
            float4 v = xg[e];
            int f = f4 << 2;
            xs[(f + 0) * SAMPLES_PB + s] = v.x;
            xs[(f + 1) * SAMPLES_PB + s] = v.y;
            xs[(f + 2) * SAMPLES_PB + s] = v.z;
            xs[(f + 3) * SAMPLES_PB + s] = v.w;
        }
    }
    for (int i = tid; i < SAMPLES_PB * N_CLASSES; i += BLOCK)
        sums[i] = 0.0f;
    __syncthreads();

    // Lane layout: sLocal = tid & 31 (32 lanes of a wave walk the SAME tree
    // -> node loads span <=504 B), j = tid >> 5 picks the tree chunk.
    const int sLocal = tid & (SAMPLES_PB - 1);
    const int j      = tid >> 5;                 // 0..7
    const int t0 = j * TREES_PT;                 // multiple of 10 -> class = u

    float acc[N_CLASSES];
    #pragma unroll
    for (int k = 0; k < N_CLASSES; ++k) acc[k] = 0.0f;

    for (int i = 0; i < TREES_PT; i += UNROLL) {
        const int tt = t0 + i;
        int idx[UNROLL];
        #pragma unroll
        for (int u = 0; u < UNROLL; ++u) idx[u] = 0;

        #pragma unroll
        for (int d = 0; d < DEPTH; ++d) {
            int   f[UNROLL];
            float thr[UNROLL];
            #pragma unroll
            for (int u = 0; u < UNROLL; ++u) {
                if (PACKED) {
                    int2 nd = nodes[((tt + u) << 6) + idx[u]];
                    f[u]   = nd.x;
                    thr[u] = __int_as_float(nd.y);
                } else {
                    int base = (tt + u) * N_INTERNAL + idx[u];
                    f[u]   = features[base];
                    thr[u] = thresholds[base];
                }
            }
            float xv[UNROLL];
            #pragma unroll
            for (int u = 0; u < UNROLL; ++u)
                xv[u] = xs[f[u] * SAMPLES_PB + sLocal];
            #pragma unroll
            for (int u = 0; u < UNROLL; ++u)
                idx[u] = 2 * idx[u] + 1 + (xv[u] > thr[u] ? 1 : 0);
        }
        #pragma unroll
        for (int u = 0; u < UNROLL; ++u) {
            float lv = leaf_values[((size_t)(tt + u) << 6) + (idx[u] - N_INTERNAL)];
            acc[u] += lv;   // tree (tt+u) % 10 == u  -> class u
        }
    }

    #pragma unroll
    for (int k = 0; k < N_CLASSES; ++k)
        atomicAdd(&sums[sLocal * N_CLASSES + k], acc[k]);
    __syncthreads();

    for (int e = tid; e < SAMPLES_PB * N_CLASSES; e += BLOCK) {
        int s = e / N_CLASSES;
        int k = e - s * N_CLASSES;
        out[(size_t)(sample0 + s) * N_CLASSES + k] = init_out[k] + LR * sums[e];
    }
}

extern "C" void kernel_launch(void* const* d_in, const int* in_sizes, int n_in,
                              void* d_out, int out_size, void* d_ws, size_t ws_size,
                              hipStream_t stream) {
    const float* x          = (const float*)d_in[0];
    const int*   features   = (const int*)d_in[1];
    const float* thresholds = (const float*)d_in[2];
    const float* leafvals   = (const float*)d_in[3];
    const float* init_out   = (const float*)d_in[4];
    float*       out        = (float*)d_out;

    const size_t packed_bytes = (size_t)N_TREES * 64 * sizeof(int2);  // 2 MB
    const int grid = BATCH / SAMPLES_PB;                              // 1024

    if (ws_size >= packed_bytes) {
        int2* nodes = (int2*)d_ws;
        int n = N_TREES * N_INTERNAL;
        pack_nodes_kernel<<<(n + 255) / 256, 256, 0, stream>>>(features, thresholds, nodes);
        gbt_eval_kernel<true><<<grid, BLOCK, 0, stream>>>(
            x, nodes, nullptr, nullptr, leafvals, init_out, out);
    } else {
        gbt_eval_kernel<false><<<grid, BLOCK, 0, stream>>>(
            x, nullptr, features, thresholds, leafvals, init_out, out);
    }
}